// Round 16
// baseline (964.301 us; speedup 1.0000x reference)
//
#include <hip/hip_runtime.h>
#include <hip/hip_bf16.h>

typedef __attribute__((ext_vector_type(4))) float f32x4;
typedef __attribute__((ext_vector_type(8))) short s16x8;
typedef __attribute__((ext_vector_type(4))) short s16x4;

#define AS1 __attribute__((address_space(1)))
#define AS3 __attribute__((address_space(3)))

__device__ __forceinline__ short f2bf(float f) {
    union { float f; unsigned u; } a; a.f = f;
    unsigned r = a.u + 0x7fff + ((a.u >> 16) & 1);
    return (short)(r >> 16);
}

__device__ __forceinline__ unsigned pk_bf16(float a, float b) {
    unsigned r;
    asm("v_cvt_pk_bf16_f32 %0, %1, %2" : "=v"(r) : "v"(a), "v"(b));
    return r;
}

// ---------------- conversion kernels ----------------

__global__ __launch_bounds__(256) void convert_f32_bf16(const float* __restrict__ in,
                                                        short* __restrict__ out, int n4) {
    int i = blockIdx.x * 256 + threadIdx.x;
    if (i < n4) {
        f32x4 v = *(const f32x4*)(in + (long)i * 4);
        s16x4 o;
        o.x = f2bf(v.x); o.y = f2bf(v.y); o.z = f2bf(v.z); o.w = f2bf(v.w);
        *(s16x4*)(out + (long)i * 4) = o;
    }
}

// src [K][N] f32 -> dst [N][K] bf16
__global__ __launch_bounds__(256) void transpose_w(const float* __restrict__ src,
                                                   short* __restrict__ dst, int K, int N) {
    __shared__ short t[64][65];
    int k0 = blockIdx.x * 64, n0 = blockIdx.y * 64;
    int tid = threadIdx.x;
    for (int i = tid; i < 64 * 64; i += 256) {
        int r = i >> 6, c = i & 63;
        t[r][c] = f2bf(src[(long)(k0 + r) * N + n0 + c]);
    }
    __syncthreads();
    for (int i = tid; i < 64 * 64; i += 256) {
        int r = i >> 6, c = i & 63;
        dst[(long)(n0 + r) * K + k0 + c] = t[c][r];
    }
}

// ---------------- GEMM v9: 256^2 tile, 8 waves, BK=32, 2-phase interleave, 2 blocks/CU ----
// Same interleaved counted-vmcnt discipline as the 8-phase template, sized so TWO blocks
// fit per CU (64 KB LDS static, launch_bounds(512,4) -> 4 waves/SIMD): fixes the 1-block/CU
// starvation + 2.25-pass tail that nulled rounds 8/13/14/15.
// Queue (1 load/thread per half, 2 halves per operand-tile):
//   prologue: A0,B0 (4) + A1 (2); vmcnt(2)
//   P1(t): rd A(4)+B03(4); stg B(t+1)x2; bar; lgkm0; 16 MFMA; bar
//   P2(t): rd B47(4);      stg A(t+2)x2; vmcnt(2); bar; lgkm0; 16 MFMA; bar
// vmcnt(2) retires exactly {A(t+1),B(t+1)}, leaves A(t+2) in flight (never 0 steady-state).
// Overwrite audit: STG_B->buf^1 region last read P2(t-1) (<=1 barrier before); STG_A->buf
// region last read P1(t) (1 barrier before). Superrow XOR swizzle (verified, 0 conflicts).

template <int MODE>
__global__ __launch_bounds__(512, 4) void gemm9(const short* __restrict__ A,
                                                const short* __restrict__ BT,
                                                const float* __restrict__ bias,
                                                float* __restrict__ outF,
                                                short* __restrict__ q_,
                                                short* __restrict__ k_,
                                                short* __restrict__ v_,
                                                int M, int N, int K) {
    __shared__ short lA[2][8192];   // [buf][128 superrows][8 slots][8 shorts] = 16KB
    __shared__ short lB[2][8192];

    int tid = threadIdx.x;
    int lane = tid & 63, wid = tid >> 6;
    int wm = wid >> 1, wn = wid & 1;
    int lo = lane & 15, hi = lane >> 4;
    int srlo = lo >> 1, rpar = (lo & 1) << 2;

    // XCD-grouped bijective block swizzle (gridDim.x % 8 == 0)
    int bid = blockIdx.x;
    int swz = (bid & 7) * ((int)gridDim.x >> 3) + (bid >> 3);
    int NX = N >> 8;
    int bx = swz % NX, by = swz / NX;
    int m0 = by * 256, n0 = bx * 256;

    const short* Ag = A + (long)m0 * K;
    const short* Bg = BT + (long)n0 * K;

    f32x4 acc[4][8];
#pragma unroll
    for (int i = 0; i < 4; ++i)
#pragma unroll
        for (int j = 0; j < 8; ++j) acc[i][j] = (f32x4){0.f, 0.f, 0.f, 0.f};

    // staging lane constants (superrow swizzle, pre-swizzled source)
    int srl_ = tid >> 3;            // 0..63 (superrow within half)
    int s_ = tid & 7;               // slot
    int cc_ = s_ ^ (srl_ & 7);      // inverse-swizzled chunk code
    int gp_ = cc_ >> 2;             // row parity
    int gk_ = (cc_ & 3) * 8;        // k offset (shorts)

#define STG(Xg_, Xl_, t_, h_)                                                               \
    do {                                                                                    \
        int srg_ = (h_) * 64 + srl_;                                                        \
        long grow_ = (long)(srg_ * 2 + gp_);                                                \
        __builtin_amdgcn_global_load_lds(                                                   \
            (const AS1 void*)((Xg_) + grow_ * K + (t_) * 32 + gk_),                         \
            (AS3 void*)((Xl_) + srg_ * 64 + s_ * 8), 16, 0, 0);                             \
    } while (0)

    int T = K >> 5;   // BK=32 tiles (24 for K=768)

    // prologue: tile0 A+B (4 loads), tile1 A (2 loads); vmcnt(2) -> tile0 landed
    STG(Ag, lA[0], 0, 0); STG(Ag, lA[0], 0, 1);
    STG(Bg, lB[0], 0, 0); STG(Bg, lB[0], 0, 1);
    if (T > 1) { STG(Ag, lA[1], 1, 0); STG(Ag, lA[1], 1, 1); }
    asm volatile("s_waitcnt vmcnt(2)" ::: "memory");
    __builtin_amdgcn_s_barrier();

    int soff = ((rpar + hi) ^ srlo) * 8;

    for (int t = 0; t < T; ++t) {
        int b = t & 1;
        const short* lAb = lA[b];
        const short* lBb = lB[b];

        // ---- P1: read A (4) + B ni0-3 (4); stage B(t+1)
        s16x8 a[4], b03[4];
#pragma unroll
        for (int mi = 0; mi < 4; ++mi)
            a[mi] = *(const s16x8*)(lAb + (wm * 32 + mi * 8 + srlo) * 64 + soff);
#pragma unroll
        for (int ni = 0; ni < 4; ++ni)
            b03[ni] = *(const s16x8*)(lBb + (wn * 64 + ni * 8 + srlo) * 64 + soff);
        if (t + 1 < T) { STG(Bg, lB[b ^ 1], t + 1, 0); STG(Bg, lB[b ^ 1], t + 1, 1); }
        __builtin_amdgcn_s_barrier();
        asm volatile("s_waitcnt lgkmcnt(0)" ::: "memory");
        __builtin_amdgcn_sched_barrier(0);
        __builtin_amdgcn_s_setprio(1);
#pragma unroll
        for (int mi = 0; mi < 4; ++mi)
#pragma unroll
            for (int ni = 0; ni < 4; ++ni)
                acc[mi][ni] = __builtin_amdgcn_mfma_f32_16x16x32_bf16(a[mi], b03[ni], acc[mi][ni], 0, 0, 0);
        __builtin_amdgcn_s_setprio(0);
        __builtin_amdgcn_s_barrier();

        // ---- P2: read B ni4-7 (4); stage A(t+2); counted vmcnt
        s16x8 b47[4];
#pragma unroll
        for (int ni = 0; ni < 4; ++ni)
            b47[ni] = *(const s16x8*)(lBb + (wn * 64 + (ni + 4) * 8 + srlo) * 64 + soff);
        if (t + 2 < T) {
            STG(Ag, lA[b], t + 2, 0); STG(Ag, lA[b], t + 2, 1);
            asm volatile("s_waitcnt vmcnt(2)" ::: "memory");
        } else if (t + 1 < T) {
            asm volatile("s_waitcnt vmcnt(0)" ::: "memory");
        }
        __builtin_amdgcn_s_barrier();
        asm volatile("s_waitcnt lgkmcnt(0)" ::: "memory");
        __builtin_amdgcn_sched_barrier(0);
        __builtin_amdgcn_s_setprio(1);
#pragma unroll
        for (int mi = 0; mi < 4; ++mi)
#pragma unroll
            for (int ni = 0; ni < 4; ++ni)
                acc[mi][4 + ni] = __builtin_amdgcn_mfma_f32_16x16x32_bf16(a[mi], b47[ni], acc[mi][4 + ni], 0, 0, 0);
        __builtin_amdgcn_s_setprio(0);
        __builtin_amdgcn_s_barrier();
    }
#undef STG

    // ---- epilogue
    float bs[8];
#pragma unroll
    for (int ni = 0; ni < 8; ++ni) bs[ni] = bias[n0 + wn * 128 + ni * 16 + lo];

    if (MODE == 1) {
        int bidx = m0 >> 10;
        int trow0 = (m0 & 1023) + wm * 64;
#pragma unroll
        for (int nh = 0; nh < 2; ++nh) {
            int blk = ((n0 + wn * 128) >> 6) + nh;      // 0..35, wave-uniform
            int part = (blk >= 24) ? 2 : (blk >= 12 ? 1 : 0);
            int hh = blk - part * 12;
            long gb_ = ((long)(bidx * 12 + hh)) << 16;  // *65536
            if (part == 2) {
#pragma unroll
                for (int mi = 0; mi < 4; ++mi)
#pragma unroll
                    for (int n2 = 0; n2 < 4; ++n2) {
                        int ni = nh * 4 + n2;
                        s16x4 o;
                        o.x = f2bf(acc[mi][ni][0] + bs[ni]);
                        o.y = f2bf(acc[mi][ni][1] + bs[ni]);
                        o.z = f2bf(acc[mi][ni][2] + bs[ni]);
                        o.w = f2bf(acc[mi][ni][3] + bs[ni]);
                        int tq = trow0 + mi * 16 + hi * 4;
                        *(s16x4*)(v_ + gb_ + (long)(n2 * 16 + lo) * 1024 + tq) = o;
                    }
            } else {
                short* dst = (part == 0) ? q_ : k_;
                float scl = (part == 0) ? 0.180336880f : 1.0f;  // (1/8)*log2(e) fold for q
#pragma unroll
                for (int mi = 0; mi < 4; ++mi)
#pragma unroll
                    for (int n2 = 0; n2 < 4; ++n2) {
                        int ni = nh * 4 + n2;
#pragma unroll
                        for (int r = 0; r < 4; ++r) {
                            int trow = trow0 + mi * 16 + hi * 4 + r;
                            float v = (acc[mi][ni][r] + bs[ni]) * scl;
                            dst[gb_ + (long)trow * 64 + n2 * 16 + lo] = f2bf(v);
                        }
                    }
            }
        }
    } else {
#pragma unroll
        for (int mi = 0; mi < 4; ++mi)
#pragma unroll
            for (int ni = 0; ni < 8; ++ni)
#pragma unroll
                for (int r = 0; r < 4; ++r) {
                    int gm = m0 + wm * 64 + mi * 16 + hi * 4 + r;
                    int gn = n0 + wn * 128 + ni * 16 + lo;
                    outF[(long)gm * N + gn] = acc[mi][ni][r] + bs[ni];
                }
    }
}

// ---------------- flash attention v9: 24KB LDS + defer-max (T13) — unchanged ----------------

__device__ __forceinline__ void qk_softmax(const short* __restrict__ Kb_,
                                           int kv0, int qb0, bool diag,
                                           s16x8 bq0, s16x8 bq1,
                                           f32x4 (&ov)[4], float& mrun, float& lrun,
                                           s16x8 (&ap)[2],
                                           int lo, int hi, int hi2, int sA, int sB,
                                           int sl0, int sl1) {
    f32x4 s[4];
    __builtin_amdgcn_s_setprio(1);
#pragma unroll
    for (int n = 0; n < 4; ++n) {
        const short* kr = Kb_ + (n * 16 + lo) * 64;
        s16x8 kf0 = *(const s16x8*)(kr + sl0);
        s16x8 kf1 = *(const s16x8*)(kr + sl1);
        f32x4 t = (f32x4){0.f, 0.f, 0.f, 0.f};
        t = __builtin_amdgcn_mfma_f32_16x16x32_bf16(kf0, bq0, t, 0, 0, 0);
        t = __builtin_amdgcn_mfma_f32_16x16x32_bf16(kf1, bq1, t, 0, 0, 0);
        s[n] = t;
    }
    __builtin_amdgcn_s_setprio(0);

    int qglob = qb0 + lo;
    if (diag) {
#pragma unroll
        for (int n = 0; n < 4; ++n)
#pragma unroll
            for (int r = 0; r < 4; ++r)
                if (kv0 + n * 16 + hi * 4 + r > qglob) s[n][r] = -3.0e38f;
    }
    float mx = fmaxf(fmaxf(fmaxf(s[0][0], s[0][1]), fmaxf(s[0][2], s[0][3])),
                     fmaxf(fmaxf(s[1][0], s[1][1]), fmaxf(s[1][2], s[1][3])));
    mx = fmaxf(mx, fmaxf(fmaxf(fmaxf(s[2][0], s[2][1]), fmaxf(s[2][2], s[2][3])),
                         fmaxf(fmaxf(s[3][0], s[3][1]), fmaxf(s[3][2], s[3][3]))));
    mx = fmaxf(mx, __shfl_xor(mx, 16));
    mx = fmaxf(mx, __shfl_xor(mx, 32));
    if (!__all(mx - mrun <= 8.0f)) {
        float mn = fmaxf(mrun, mx);
        float alpha = exp2f(mrun - mn);
        mrun = mn;
        lrun *= alpha;
#pragma unroll
        for (int nd = 0; nd < 4; ++nd)
#pragma unroll
            for (int r = 0; r < 4; ++r) ov[nd][r] *= alpha;
    }
    float m = mrun;
    float rs = 0.f;
#pragma unroll
    for (int n = 0; n < 4; ++n)
#pragma unroll
        for (int r = 0; r < 4; ++r) {
            float p = exp2f(s[n][r] - m);
            s[n][r] = p;
            rs += p;
        }
    rs += __shfl_xor(rs, 16);
    rs += __shfl_xor(rs, 32);
    lrun += rs;

    unsigned W[4][2];
#pragma unroll
    for (int n = 0; n < 4; ++n) {
        W[n][0] = pk_bf16(s[n][0], s[n][1]);
        W[n][1] = pk_bf16(s[n][2], s[n][3]);
    }
#pragma unroll
    for (int kc = 0; kc < 2; ++kc) {
        unsigned a0 = __shfl(W[kc * 2][0], sA), b0 = __shfl(W[kc * 2 + 1][0], sA);
        unsigned a1 = __shfl(W[kc * 2][1], sA), b1 = __shfl(W[kc * 2 + 1][1], sA);
        unsigned a2 = __shfl(W[kc * 2][0], sB), b2 = __shfl(W[kc * 2 + 1][0], sB);
        unsigned a3 = __shfl(W[kc * 2][1], sB), b3 = __shfl(W[kc * 2 + 1][1], sB);
        union { unsigned u[4]; s16x8 v; } cv;
        cv.u[0] = hi2 ? b0 : a0;
        cv.u[1] = hi2 ? b1 : a1;
        cv.u[2] = hi2 ? b2 : a2;
        cv.u[3] = hi2 ? b3 : a3;
        ap[kc] = cv.v;
    }
}

__device__ __forceinline__ void pv_accum(const short* __restrict__ Vb_,
                                         const s16x8 (&ap)[2], f32x4 (&ov)[4],
                                         int lo, int sl0, int sl1) {
    __builtin_amdgcn_s_setprio(1);
#pragma unroll
    for (int nd = 0; nd < 4; ++nd) {
        const short* vr = Vb_ + (nd * 16 + lo) * 64;
        s16x8 av0 = *(const s16x8*)(vr + sl0);
        s16x8 av1 = *(const s16x8*)(vr + sl1);
        ov[nd] = __builtin_amdgcn_mfma_f32_16x16x32_bf16(av0, ap[0], ov[nd], 0, 0, 0);
        ov[nd] = __builtin_amdgcn_mfma_f32_16x16x32_bf16(av1, ap[1], ov[nd], 0, 0, 0);
    }
    __builtin_amdgcn_s_setprio(0);
}

__device__ __forceinline__ void store_out(const f32x4 (&ov)[4], float lrun,
                                          long rowbase, int qb0, int h,
                                          int lo, int hi, short* __restrict__ y) {
    float inv = 1.0f / lrun;
    long row = (rowbase + qb0 + lo) * 768 + h * 64;
#pragma unroll
    for (int nd = 0; nd < 4; ++nd)
#pragma unroll
        for (int j2 = 0; j2 < 2; ++j2) {
            unsigned pv = pk_bf16(ov[nd][2 * j2] * inv, ov[nd][2 * j2 + 1] * inv);
            *(unsigned*)(y + row + nd * 16 + hi * 4 + 2 * j2) = pv;
        }
}

// grid 1536; block = 4 waves sharing (b,h); paired q-fragments (qp, 15-qp) -> 17 tiles.
__global__ __launch_bounds__(256) void flash_attn9(const short* __restrict__ qpk,
                                                   const short* __restrict__ kpk,
                                                   const short* __restrict__ vtg,
                                                   short* __restrict__ y) {
    __shared__ short Kb[2][4096];
    __shared__ short Vb[4096];

    int d = blockIdx.x;
    int qp = d / 192, g = d % 192;
    int h = g % 12, b = g / 12;
    int tid = threadIdx.x, lane = tid & 63, w = tid >> 6;
    int lo = lane & 15, hi = lane >> 4, hi2 = hi >> 1;
    long rowbase = (long)b * 1024;
    const short* kb_g = kpk + (long)g * 65536;
    const short* vt_g = vtg + (long)g * 65536;
    int sA = ((hi & 1) * 2) * 16 + lo, sB = sA + 16;

    int rl = lane >> 3;
    int cs8 = (((lane & 7) ^ rl)) * 8;
    int r0 = w * 8 + rl;
    int sl0 = (hi ^ (lo & 7)) * 8;
    int sl1 = ((hi + 4) ^ (lo & 7)) * 8;

    int qbA = qp * 64 + w * 16;
    int qbB = (15 - qp) * 64 + w * 16;

    f32x4 ov[4];
    float mrun = -3.0e38f, lrun = 0.f;
#pragma unroll
    for (int nd = 0; nd < 4; ++nd) ov[nd] = (f32x4){0.f, 0.f, 0.f, 0.f};
    s16x8 bq0, bq1;
    {
        const short* qrow = qpk + ((long)g * 1024 + qbA + lo) * 64;
        bq0 = *(const s16x8*)(qrow + hi * 8);
        bq1 = *(const s16x8*)(qrow + 32 + hi * 8);
    }

#define STAGE_K(kv0_, buf_)                                                                  \
    do {                                                                                     \
        _Pragma("unroll")                                                                    \
        for (int i_ = 0; i_ < 2; ++i_) {                                                     \
            int r_ = i_ * 32 + r0;                                                           \
            __builtin_amdgcn_global_load_lds(                                                \
                (const AS1 void*)(kb_g + (long)((kv0_) + r_) * 64 + cs8),                    \
                (AS3 void*)(Kb[buf_] + (i_ * 32 + w * 8) * 64), 16, 0, 0);                   \
        }                                                                                    \
    } while (0)

#define STAGE_V(kv0_)                                                                        \
    do {                                                                                     \
        _Pragma("unroll")                                                                    \
        for (int i_ = 0; i_ < 2; ++i_) {                                                     \
            int r_ = i_ * 32 + r0;                                                           \
            __builtin_amdgcn_global_load_lds(                                                \
                (const AS1 void*)(vt_g + (long)r_ * 1024 + (kv0_) + cs8),                    \
                (AS3 void*)(Vb + (i_ * 32 + w * 8) * 64), 16, 0, 0);                         \
        }                                                                                    \
    } while (0)

    STAGE_K(0, 0);
    STAGE_V(0);
    __syncthreads();

    int cur = 0;
    for (int u = 0; u < 17; ++u) {
        int nu = u + 1;
        int nkv0 = (nu <= qp) ? nu * 64 : (nu - qp - 1) * 64;
        if (nu < 17) STAGE_K(nkv0, cur ^ 1);

        bool phaseA = (u <= qp);
        int kv0 = phaseA ? u * 64 : (u - qp - 1) * 64;
        int qb0 = phaseA ? qbA : qbB;
        bool diag = phaseA ? (u == qp) : (u == 16);

        s16x8 ap[2];
        qk_softmax(Kb[cur], kv0, qb0, diag, bq0, bq1, ov, mrun, lrun, ap,
                   lo, hi, hi2, sA, sB, sl0, sl1);

        __syncthreads();   // A: drains all waves' K+V DMAs
        __builtin_amdgcn_sched_barrier(0);

        pv_accum(Vb, ap, ov, lo, sl0, sl1);

        if (phaseA && u == qp) {
            store_out(ov, lrun, rowbase, qbA, h, lo, hi, y);
            const short* qrow = qpk + ((long)g * 1024 + qbB + lo) * 64;
            bq0 = *(const s16x8*)(qrow + hi * 8);
            bq1 = *(const s16x8*)(qrow + 32 + hi * 8);
#pragma unroll
            for (int nd = 0; nd < 4; ++nd) ov[nd] = (f32x4){0.f, 0.f, 0.f, 0.f};
            mrun = -3.0e38f; lrun = 0.f;
        }

        __builtin_amdgcn_s_barrier();   // B: all waves done reading Vb
        __builtin_amdgcn_sched_barrier(0);
        if (nu < 17) STAGE_V(nkv0);
        cur ^= 1;
    }
    store_out(ov, lrun, rowbase, qbB, h, lo, hi, y);
#undef STAGE_K
#undef STAGE_V
}

// ---------------- launch ----------------

extern "C" void kernel_launch(void* const* d_in, const int* in_sizes, int n_in,
                              void* d_out, int out_size, void* d_ws, size_t ws_size,
                              hipStream_t stream) {
    const float* x      = (const float*)d_in[0];
    const float* w_attn = (const float*)d_in[1];
    const float* b_attn = (const float*)d_in[2];
    const float* w_proj = (const float*)d_in[3];
    const float* b_proj = (const float*)d_in[4];

    char* ws = (char*)d_ws;
    short* x_bf = (short*)ws;                      // 25165824 B
    short* qpk  = (short*)(ws + 25165824);         // q packed [g][1024][64]
    short* kpk  = (short*)(ws + 50331648);         // k packed [g][1024][64]
    short* vt   = (short*)(ws + 75497472);         // V^T [g][64][1024] (direct)
    short* yb   = (short*)(ws + 100663296);
    short* waT  = (short*)(ws + 125829120);
    short* wpT  = (short*)(ws + 129368064);

    // x -> bf16
    convert_f32_bf16<<<dim3(12288), dim3(256), 0, stream>>>(x, x_bf, 3145728);
    // weight transposes (to [N][K] bf16)
    transpose_w<<<dim3(12, 36), dim3(256), 0, stream>>>(w_attn, waT, 768, 2304);
    transpose_w<<<dim3(12, 12), dim3(256), 0, stream>>>(w_proj, wpT, 768, 768);
    // QKV projection (+bias); q/k packed, V written directly transposed. 9x64=576 blocks.
    gemm9<1><<<dim3(576), dim3(512), 0, stream>>>(x_bf, waT, b_attn,
                                                  (float*)nullptr, qpk, kpk, vt,
                                                  16384, 2304, 768);
    // causal flash attention (24KB LDS, defer-max)
    flash_attn9<<<dim3(1536), dim3(256), 0, stream>>>(qpk, kpk, vt, yb);
    // output projection -> fp32. 3x64=192 blocks.
    gemm9<0><<<dim3(192), dim3(512), 0, stream>>>(yb, wpT, b_proj,
                                                  (float*)d_out, (short*)nullptr,
                                                  (short*)nullptr, (short*)nullptr,
                                                  16384, 768, 768);
}

// Round 17
// 201.187 us; speedup vs baseline: 4.7931x; 4.7931x over previous
//
#include <hip/hip_runtime.h>
#include <hip/hip_bf16.h>

typedef __attribute__((ext_vector_type(4))) float f32x4;
typedef __attribute__((ext_vector_type(8))) short s16x8;
typedef __attribute__((ext_vector_type(4))) short s16x4;

#define AS1 __attribute__((address_space(1)))
#define AS3 __attribute__((address_space(3)))

__device__ __forceinline__ short f2bf(float f) {
    union { float f; unsigned u; } a; a.f = f;
    unsigned r = a.u + 0x7fff + ((a.u >> 16) & 1);
    return (short)(r >> 16);
}

__device__ __forceinline__ unsigned pk_bf16(float a, float b) {
    unsigned r;
    asm("v_cvt_pk_bf16_f32 %0, %1, %2" : "=v"(r) : "v"(a), "v"(b));
    return r;
}

// ---------------- conversion kernels ----------------

__global__ __launch_bounds__(256) void convert_f32_bf16(const float* __restrict__ in,
                                                        short* __restrict__ out, int n4) {
    int i = blockIdx.x * 256 + threadIdx.x;
    if (i < n4) {
        f32x4 v = *(const f32x4*)(in + (long)i * 4);
        s16x4 o;
        o.x = f2bf(v.x); o.y = f2bf(v.y); o.z = f2bf(v.z); o.w = f2bf(v.w);
        *(s16x4*)(out + (long)i * 4) = o;
    }
}

// src [K][N] f32 -> dst [N][K] bf16
__global__ __launch_bounds__(256) void transpose_w(const float* __restrict__ src,
                                                   short* __restrict__ dst, int K, int N) {
    __shared__ short t[64][65];
    int k0 = blockIdx.x * 64, n0 = blockIdx.y * 64;
    int tid = threadIdx.x;
    for (int i = tid; i < 64 * 64; i += 256) {
        int r = i >> 6, c = i & 63;
        t[r][c] = f2bf(src[(long)(k0 + r) * N + n0 + c]);
    }
    __syncthreads();
    for (int i = tid; i < 64 * 64; i += 256) {
        int r = i >> 6, c = i & 63;
        dst[(long)(n0 + r) * K + k0 + c] = t[c][r];
    }
}

// ---------------- GEMM: 128^2 tile, 4 waves, BK=64, superrow-swizzled LDS ----------------
// (round-12 proven config: 32KB LDS, 5 blocks/CU, 2-barrier loop — best measured)
// MODE 0: f32 out + bias. MODE 1: scatter q/k packed [g][1024][64]; V written TRANSPOSED
// directly into vt [g][64][1024].

template <int MODE>
__global__ __launch_bounds__(256) void gemm_bt(const short* __restrict__ A,
                                               const short* __restrict__ BT,
                                               const float* __restrict__ bias,
                                               float* __restrict__ outF,
                                               short* __restrict__ q_,
                                               short* __restrict__ k_,
                                               short* __restrict__ v_,
                                               int M, int N, int K) {
    __shared__ short lA[2 * 64 * 64];
    __shared__ short lB[2 * 64 * 64];
    int tid = threadIdx.x;
    int lane = tid & 63, w = tid >> 6;
    int wr = w >> 1, wc = w & 1;
    int lo = lane & 15, hi = lane >> 4;

    int bid = blockIdx.x;
    int swz = (bid & 7) * ((int)gridDim.x >> 3) + (bid >> 3);
    int NX = N >> 7;
    int bx = swz % NX, by = swz / NX;
    int m0 = by * 128, n0 = bx * 128;

    f32x4 acc[4][4];
#pragma unroll
    for (int i = 0; i < 4; ++i)
#pragma unroll
        for (int j = 0; j < 4; ++j) acc[i][j] = (f32x4){0.f, 0.f, 0.f, 0.f};

    const short* Abase = A + (long)m0 * K;
    const short* Bbase = BT + (long)n0 * K;

    int lr = lane >> 3;
    int cc = (lane & 7) ^ lr;
    int growoff = cc >> 2;
    int gcol = (cc & 3) * 8;

    int srlo = lo >> 1;
    int rpar = (lo & 1) << 2;

    for (int k0 = 0; k0 < K; k0 += 64) {
        __syncthreads();
#pragma unroll
        for (int kk = 0; kk < 2; ++kk)
#pragma unroll
            for (int j = 0; j < 2; ++j) {
                int sr = w * 16 + j * 8 + lr;
                long grow = (long)(sr * 2 + growoff);
                const short* ga = Abase + grow * K + k0 + kk * 32 + gcol;
                const short* gb = Bbase + grow * K + k0 + kk * 32 + gcol;
                short* da = lA + kk * 4096 + (w * 16 + j * 8) * 64;
                short* db = lB + kk * 4096 + (w * 16 + j * 8) * 64;
                __builtin_amdgcn_global_load_lds((const AS1 void*)ga, (AS3 void*)da, 16, 0, 0);
                __builtin_amdgcn_global_load_lds((const AS1 void*)gb, (AS3 void*)db, 16, 0, 0);
            }
        __syncthreads();

#pragma unroll
        for (int kk = 0; kk < 2; ++kk) {
            s16x8 a[4], b[4];
#pragma unroll
            for (int mi = 0; mi < 4; ++mi)
                a[mi] = *(const s16x8*)(lA + kk * 4096 + (wr * 32 + mi * 8 + srlo) * 64 +
                                        ((rpar + hi) ^ srlo) * 8);
#pragma unroll
            for (int ni = 0; ni < 4; ++ni)
                b[ni] = *(const s16x8*)(lB + kk * 4096 + (wc * 32 + ni * 8 + srlo) * 64 +
                                        ((rpar + hi) ^ srlo) * 8);
#pragma unroll
            for (int mi = 0; mi < 4; ++mi)
#pragma unroll
                for (int ni = 0; ni < 4; ++ni)
                    acc[mi][ni] = __builtin_amdgcn_mfma_f32_16x16x32_bf16(a[mi], b[ni], acc[mi][ni], 0, 0, 0);
        }
    }

    float bs[4];
#pragma unroll
    for (int ni = 0; ni < 4; ++ni) bs[ni] = bias[n0 + wc * 64 + ni * 16 + lo];

    if (MODE == 1) {
        int blk = (n0 + wc * 64) >> 6;                  // 0..35 (wave-uniform)
        int part = (blk >= 24) ? 2 : (blk >= 12 ? 1 : 0);
        int hh = blk - part * 12;
        int bidx = m0 >> 10;
        int trow0 = (m0 & 1023) + wr * 64;
        long gb_ = ((long)(bidx * 12 + hh)) << 16;       // *65536
        if (part == 2) {
            // V: write transposed [g][d][t]; r=0..3 consecutive in t -> one s16x4 store
#pragma unroll
            for (int mi = 0; mi < 4; ++mi)
#pragma unroll
                for (int ni = 0; ni < 4; ++ni) {
                    s16x4 o;
                    o.x = f2bf(acc[mi][ni][0] + bs[ni]);
                    o.y = f2bf(acc[mi][ni][1] + bs[ni]);
                    o.z = f2bf(acc[mi][ni][2] + bs[ni]);
                    o.w = f2bf(acc[mi][ni][3] + bs[ni]);
                    int tq = trow0 + mi * 16 + hi * 4;
                    *(s16x4*)(v_ + gb_ + (long)(ni * 16 + lo) * 1024 + tq) = o;
                }
        } else {
            short* dst = (part == 0) ? q_ : k_;
            float scl = (part == 0) ? 0.180336880f : 1.0f;  // (1/8)*log2(e) fold for q
#pragma unroll
            for (int mi = 0; mi < 4; ++mi)
#pragma unroll
                for (int ni = 0; ni < 4; ++ni)
#pragma unroll
                    for (int r = 0; r < 4; ++r) {
                        int trow = trow0 + mi * 16 + hi * 4 + r;
                        float v = (acc[mi][ni][r] + bs[ni]) * scl;
                        dst[gb_ + (long)trow * 64 + ni * 16 + lo] = f2bf(v);
                    }
        }
    } else {
#pragma unroll
        for (int mi = 0; mi < 4; ++mi)
#pragma unroll
            for (int ni = 0; ni < 4; ++ni)
#pragma unroll
                for (int r = 0; r < 4; ++r) {
                    int gm = m0 + wr * 64 + mi * 16 + hi * 4 + r;
                    int gn = n0 + wc * 64 + ni * 16 + lo;
                    outF[(long)gm * N + gn] = acc[mi][ni][r] + bs[ni];
                }
    }
}

// ---------------- flash attention v9: 24KB LDS + defer-max (T13) ----------------

__device__ __forceinline__ void qk_softmax(const short* __restrict__ Kb_,
                                           int kv0, int qb0, bool diag,
                                           s16x8 bq0, s16x8 bq1,
                                           f32x4 (&ov)[4], float& mrun, float& lrun,
                                           s16x8 (&ap)[2],
                                           int lo, int hi, int hi2, int sA, int sB,
                                           int sl0, int sl1) {
    f32x4 s[4];
    __builtin_amdgcn_s_setprio(1);
#pragma unroll
    for (int n = 0; n < 4; ++n) {
        const short* kr = Kb_ + (n * 16 + lo) * 64;
        s16x8 kf0 = *(const s16x8*)(kr + sl0);
        s16x8 kf1 = *(const s16x8*)(kr + sl1);
        f32x4 t = (f32x4){0.f, 0.f, 0.f, 0.f};
        t = __builtin_amdgcn_mfma_f32_16x16x32_bf16(kf0, bq0, t, 0, 0, 0);
        t = __builtin_amdgcn_mfma_f32_16x16x32_bf16(kf1, bq1, t, 0, 0, 0);
        s[n] = t;
    }
    __builtin_amdgcn_s_setprio(0);

    int qglob = qb0 + lo;
    if (diag) {
#pragma unroll
        for (int n = 0; n < 4; ++n)
#pragma unroll
            for (int r = 0; r < 4; ++r)
                if (kv0 + n * 16 + hi * 4 + r > qglob) s[n][r] = -3.0e38f;
    }
    float mx = fmaxf(fmaxf(fmaxf(s[0][0], s[0][1]), fmaxf(s[0][2], s[0][3])),
                     fmaxf(fmaxf(s[1][0], s[1][1]), fmaxf(s[1][2], s[1][3])));
    mx = fmaxf(mx, fmaxf(fmaxf(fmaxf(s[2][0], s[2][1]), fmaxf(s[2][2], s[2][3])),
                         fmaxf(fmaxf(s[3][0], s[3][1]), fmaxf(s[3][2], s[3][3]))));
    mx = fmaxf(mx, __shfl_xor(mx, 16));
    mx = fmaxf(mx, __shfl_xor(mx, 32));
    // defer-max (T13, THR=8 log2-domain): skip O-rescale when max growth is small.
    if (!__all(mx - mrun <= 8.0f)) {
        float mn = fmaxf(mrun, mx);
        float alpha = exp2f(mrun - mn);
        mrun = mn;
        lrun *= alpha;
#pragma unroll
        for (int nd = 0; nd < 4; ++nd)
#pragma unroll
            for (int r = 0; r < 4; ++r) ov[nd][r] *= alpha;
    }
    float m = mrun;
    float rs = 0.f;
#pragma unroll
    for (int n = 0; n < 4; ++n)
#pragma unroll
        for (int r = 0; r < 4; ++r) {
            float p = exp2f(s[n][r] - m);
            s[n][r] = p;
            rs += p;
        }
    rs += __shfl_xor(rs, 16);
    rs += __shfl_xor(rs, 32);
    lrun += rs;

    unsigned W[4][2];
#pragma unroll
    for (int n = 0; n < 4; ++n) {
        W[n][0] = pk_bf16(s[n][0], s[n][1]);
        W[n][1] = pk_bf16(s[n][2], s[n][3]);
    }
#pragma unroll
    for (int kc = 0; kc < 2; ++kc) {
        unsigned a0 = __shfl(W[kc * 2][0], sA), b0 = __shfl(W[kc * 2 + 1][0], sA);
        unsigned a1 = __shfl(W[kc * 2][1], sA), b1 = __shfl(W[kc * 2 + 1][1], sA);
        unsigned a2 = __shfl(W[kc * 2][0], sB), b2 = __shfl(W[kc * 2 + 1][0], sB);
        unsigned a3 = __shfl(W[kc * 2][1], sB), b3 = __shfl(W[kc * 2 + 1][1], sB);
        union { unsigned u[4]; s16x8 v; } cv;
        cv.u[0] = hi2 ? b0 : a0;
        cv.u[1] = hi2 ? b1 : a1;
        cv.u[2] = hi2 ? b2 : a2;
        cv.u[3] = hi2 ? b3 : a3;
        ap[kc] = cv.v;
    }
}

__device__ __forceinline__ void pv_accum(const short* __restrict__ Vb_,
                                         const s16x8 (&ap)[2], f32x4 (&ov)[4],
                                         int lo, int sl0, int sl1) {
    __builtin_amdgcn_s_setprio(1);
#pragma unroll
    for (int nd = 0; nd < 4; ++nd) {
        const short* vr = Vb_ + (nd * 16 + lo) * 64;
        s16x8 av0 = *(const s16x8*)(vr + sl0);
        s16x8 av1 = *(const s16x8*)(vr + sl1);
        ov[nd] = __builtin_amdgcn_mfma_f32_16x16x32_bf16(av0, ap[0], ov[nd], 0, 0, 0);
        ov[nd] = __builtin_amdgcn_mfma_f32_16x16x32_bf16(av1, ap[1], ov[nd], 0, 0, 0);
    }
    __builtin_amdgcn_s_setprio(0);
}

__device__ __forceinline__ void store_out(const f32x4 (&ov)[4], float lrun,
                                          long rowbase, int qb0, int h,
                                          int lo, int hi, short* __restrict__ y) {
    float inv = 1.0f / lrun;
    long row = (rowbase + qb0 + lo) * 768 + h * 64;
#pragma unroll
    for (int nd = 0; nd < 4; ++nd)
#pragma unroll
        for (int j2 = 0; j2 < 2; ++j2) {
            unsigned pv = pk_bf16(ov[nd][2 * j2] * inv, ov[nd][2 * j2 + 1] * inv);
            *(unsigned*)(y + row + nd * 16 + hi * 4 + 2 * j2) = pv;
        }
}

// grid 1536; block = 4 waves sharing (b,h); paired q-fragments (qp, 15-qp) -> 17 tiles.
// K double-buffered (16KB), V single-buffered (8KB) -> 24KB -> 6 blocks/CU resident.
__global__ __launch_bounds__(256) void flash_attn9(const short* __restrict__ qpk,
                                                   const short* __restrict__ kpk,
                                                   const short* __restrict__ vtg,
                                                   short* __restrict__ y) {
    __shared__ short Kb[2][4096];
    __shared__ short Vb[4096];

    int d = blockIdx.x;
    int qp = d / 192, g = d % 192;
    int h = g % 12, b = g / 12;
    int tid = threadIdx.x, lane = tid & 63, w = tid >> 6;
    int lo = lane & 15, hi = lane >> 4, hi2 = hi >> 1;
    long rowbase = (long)b * 1024;
    const short* kb_g = kpk + (long)g * 65536;
    const short* vt_g = vtg + (long)g * 65536;
    int sA = ((hi & 1) * 2) * 16 + lo, sB = sA + 16;

    int rl = lane >> 3;
    int cs8 = (((lane & 7) ^ rl)) * 8;
    int r0 = w * 8 + rl;
    int sl0 = (hi ^ (lo & 7)) * 8;
    int sl1 = ((hi + 4) ^ (lo & 7)) * 8;

    int qbA = qp * 64 + w * 16;
    int qbB = (15 - qp) * 64 + w * 16;

    f32x4 ov[4];
    float mrun = -3.0e38f, lrun = 0.f;
#pragma unroll
    for (int nd = 0; nd < 4; ++nd) ov[nd] = (f32x4){0.f, 0.f, 0.f, 0.f};
    s16x8 bq0, bq1;
    {
        const short* qrow = qpk + ((long)g * 1024 + qbA + lo) * 64;
        bq0 = *(const s16x8*)(qrow + hi * 8);
        bq1 = *(const s16x8*)(qrow + 32 + hi * 8);
    }

#define STAGE_K(kv0_, buf_)                                                                  \
    do {                                                                                     \
        _Pragma("unroll")                                                                    \
        for (int i_ = 0; i_ < 2; ++i_) {                                                     \
            int r_ = i_ * 32 + r0;                                                           \
            __builtin_amdgcn_global_load_lds(                                                \
                (const AS1 void*)(kb_g + (long)((kv0_) + r_) * 64 + cs8),                    \
                (AS3 void*)(Kb[buf_] + (i_ * 32 + w * 8) * 64), 16, 0, 0);                   \
        }                                                                                    \
    } while (0)

#define STAGE_V(kv0_)                                                                        \
    do {                                                                                     \
        _Pragma("unroll")                                                                    \
        for (int i_ = 0; i_ < 2; ++i_) {                                                     \
            int r_ = i_ * 32 + r0;                                                           \
            __builtin_amdgcn_global_load_lds(                                                \
                (const AS1 void*)(vt_g + (long)r_ * 1024 + (kv0_) + cs8),                    \
                (AS3 void*)(Vb + (i_ * 32 + w * 8) * 64), 16, 0, 0);                         \
        }                                                                                    \
    } while (0)

    STAGE_K(0, 0);
    STAGE_V(0);
    __syncthreads();

    int cur = 0;
    for (int u = 0; u < 17; ++u) {
        int nu = u + 1;
        int nkv0 = (nu <= qp) ? nu * 64 : (nu - qp - 1) * 64;
        if (nu < 17) STAGE_K(nkv0, cur ^ 1);

        bool phaseA = (u <= qp);
        int kv0 = phaseA ? u * 64 : (u - qp - 1) * 64;
        int qb0 = phaseA ? qbA : qbB;
        bool diag = phaseA ? (u == qp) : (u == 16);

        s16x8 ap[2];
        qk_softmax(Kb[cur], kv0, qb0, diag, bq0, bq1, ov, mrun, lrun, ap,
                   lo, hi, hi2, sA, sB, sl0, sl1);

        __syncthreads();   // A: drains all waves' K+V DMAs
        __builtin_amdgcn_sched_barrier(0);

        pv_accum(Vb, ap, ov, lo, sl0, sl1);

        if (phaseA && u == qp) {
            store_out(ov, lrun, rowbase, qbA, h, lo, hi, y);
            const short* qrow = qpk + ((long)g * 1024 + qbB + lo) * 64;
            bq0 = *(const s16x8*)(qrow + hi * 8);
            bq1 = *(const s16x8*)(qrow + 32 + hi * 8);
#pragma unroll
            for (int nd = 0; nd < 4; ++nd) ov[nd] = (f32x4){0.f, 0.f, 0.f, 0.f};
            mrun = -3.0e38f; lrun = 0.f;
        }

        __builtin_amdgcn_s_barrier();   // B: all waves done reading Vb
        __builtin_amdgcn_sched_barrier(0);
        if (nu < 17) STAGE_V(nkv0);
        cur ^= 1;
    }
    store_out(ov, lrun, rowbase, qbB, h, lo, hi, y);
#undef STAGE_K
#undef STAGE_V
}

// ---------------- launch ----------------

extern "C" void kernel_launch(void* const* d_in, const int* in_sizes, int n_in,
                              void* d_out, int out_size, void* d_ws, size_t ws_size,
                              hipStream_t stream) {
    const float* x      = (const float*)d_in[0];
    const float* w_attn = (const float*)d_in[1];
    const float* b_attn = (const float*)d_in[2];
    const float* w_proj = (const float*)d_in[3];
    const float* b_proj = (const float*)d_in[4];

    char* ws = (char*)d_ws;
    short* x_bf = (short*)ws;                      // 25165824 B
    short* qpk  = (short*)(ws + 25165824);         // q packed [g][1024][64]
    short* kpk  = (short*)(ws + 50331648);         // k packed [g][1024][64]
    short* vt   = (short*)(ws + 75497472);         // V^T [g][64][1024] (direct)
    short* yb   = (short*)(ws + 100663296);
    short* waT  = (short*)(ws + 125829120);
    short* wpT  = (short*)(ws + 129368064);

    // x -> bf16
    convert_f32_bf16<<<dim3(12288), dim3(256), 0, stream>>>(x, x_bf, 3145728);
    // weight transposes (to [N][K] bf16)
    transpose_w<<<dim3(12, 36), dim3(256), 0, stream>>>(w_attn, waT, 768, 2304);
    transpose_w<<<dim3(12, 12), dim3(256), 0, stream>>>(w_proj, wpT, 768, 768);
    // QKV projection (+bias); q/k packed, V written directly transposed
    gemm_bt<1><<<dim3(2304), dim3(256), 0, stream>>>(x_bf, waT, b_attn,
                                                     (float*)nullptr, qpk, kpk, vt,
                                                     16384, 2304, 768);
    // causal flash attention (24KB LDS, defer-max)
    flash_attn9<<<dim3(1536), dim3(256), 0, stream>>>(qpk, kpk, vt, yb);
    // output projection -> fp32
    gemm_bt<0><<<dim3(768), dim3(256), 0, stream>>>(yb, wpT, b_proj,
                                                    (float*)d_out, (short*)nullptr,
                                                    (short*)nullptr, (short*)nullptr,
                                                    16384, 768, 768);
}